// Round 7
// baseline (176.561 us; speedup 1.0000x reference)
//
#include <hip/hip_runtime.h>

#define NB 4
#define NN 4096
#define NT 16
#define NC 64
#define NE 32768
#define XR 72   // LDS tile row stride (bf16 elems); 144B = 16B-aligned, bank-spread

typedef unsigned int uint;
typedef unsigned short ushort;

typedef short bf16x8 __attribute__((ext_vector_type(8)));
typedef float f32x4 __attribute__((ext_vector_type(4)));

union ABu { uint2 u2[2]; bf16x8 v; };

__device__ inline ushort f2b(float f) {
  union { float f; uint u; } v; v.f = f;
  uint r = v.u + 0x7FFF + ((v.u >> 16) & 1);
  return (ushort)(r >> 16);
}
__device__ inline float blo(uint u) { union { uint i; float f; } v; v.i = u << 16; return v.f; }
__device__ inline float bhi(uint u) { union { uint i; float f; } v; v.i = u & 0xffff0000u; return v.f; }

// ---------------- prep: weight packing + count zeroing (merged) ----------------
// Bpack fragment layout (bf16): Bp[(((s*8+nt)*64+l)*8)+j] = B[kappa][o]
//   kappa = 32s + 4*(l>>4) + (j&3) + 16*(j>>2), o = nt*16 + (l&15)
//   conv B: B[c + 64*kk][o] = W[o,c,kk];  linear B: B[c][d] = Wg[d,c]
__global__ void k_prep(const float* __restrict__ W1, const float* __restrict__ W2,
                       const float* __restrict__ Wg,
                       ushort* __restrict__ Bp1, ushort* __restrict__ Bp2,
                       ushort* __restrict__ Wgp, int* __restrict__ count) {
  int i = blockIdx.x * blockDim.x + threadIdx.x;
  if (i < 24576) {
    int j = i & 7, l = (i >> 3) & 63, nt = (i >> 9) & 7, s = i >> 12;
    int kap = 32 * s + 4 * (l >> 4) + (j & 3) + 16 * (j >> 2);
    int c = kap & 63, kk = kap >> 6, o = nt * 16 + (l & 15);
    Bp1[i] = f2b(W1[o * 192 + c * 3 + kk]);
    Bp2[i] = f2b(W2[o * 192 + c * 3 + kk]);
  } else if (i < 28672) {
    int i2 = i - 24576;
    int j = i2 & 7, l = (i2 >> 3) & 63, nt2 = (i2 >> 9) & 3, s2 = i2 >> 11;
    int kap = 32 * s2 + 4 * (l >> 4) + (j & 3) + 16 * (j >> 2);
    int d = nt2 * 16 + (l & 15);
    Wgp[i2] = f2b(Wg[d * 64 + kap]);
  } else {
    count[i - 28672] = 0;
  }
}

__global__ void k_count(const int* __restrict__ src, int* __restrict__ count) {
  int e = blockIdx.x * blockDim.x + threadIdx.x;
  if (e < NE) atomicAdd(&count[src[e]], 1);
}

__global__ void k_scan(const int* __restrict__ count, int* __restrict__ offsets,
                       int* __restrict__ cursor) {
  __shared__ int part[256];
  int tid = threadIdx.x;
  int base = tid * 16;
  int s = 0;
  for (int i = 0; i < 16; ++i) s += count[base + i];
  part[tid] = s;
  __syncthreads();
  if (tid == 0) {
    int r = 0;
    for (int i = 0; i < 256; ++i) { int t = part[i]; part[i] = r; r += t; }
    offsets[NN] = r;
  }
  __syncthreads();
  int r = part[tid];
  for (int i = 0; i < 16; ++i) {
    offsets[base + i] = r;
    cursor[base + i] = r;
    r += count[base + i];
  }
}

__global__ void k_place(const int* __restrict__ src, int* __restrict__ cursor,
                        int* __restrict__ esort) {
  int e = blockIdx.x * blockDim.x + threadIdx.x;
  if (e < NE) {
    int p = atomicAdd(&cursor[src[e]], 1);
    esort[p] = e;
  }
}

// ---------------- GLU1(MFMA) + GCN-linear(MFMA): 1 node/block, 2 waves ----------------
// Compact tile Xs[b][tp][c], tp=t+1 (rows 0,17 zero). Conv expansion at read time.
// launch_bounds(128,2): VGPR cap ~256 — pipeline regs must stay live without spill;
// (128,6) caps at ~85 -> acc spill -> 300MB HBM RMW (R5 lesson). Watch FETCH for scratch.
__global__ __launch_bounds__(128, 2) void k_glu1lin(
    const float* __restrict__ x, const ushort* __restrict__ Bp1,
    const float* __restrict__ b1, const ushort* __restrict__ Wgp,
    const float* __restrict__ bg, ushort* __restrict__ y) {
  __shared__ ushort As[4 * 18 * XR];   // 10368 B
  int tid = threadIdx.x;
  int n = blockIdx.x;
  int w = tid >> 6, l = tid & 63, m = l & 15, g4 = l >> 4;

  // zero pad rows tp=0,17 per batch
  {
    int strip = tid >> 4, b = strip >> 1, tp = (strip & 1) ? 17 : 0;
    int c4 = (tid & 15) * 4;
    *(uint2*)&As[(b * 18 + tp) * XR + c4] = make_uint2(0, 0);
  }
  // stage x -> compact bf16 tile
  const float4* x4 = (const float4*)x;
  #pragma unroll
  for (int q = 0; q < 8; ++q) {
    int f4 = q * 128 + tid;
    int b = f4 >> 8, rem = f4 & 255, tau = rem >> 4, c4i = rem & 15;
    float4 v = x4[((b * NN + n) * 16 + tau) * 16 + c4i];
    uint2 p;
    p.x = (uint)f2b(v.x) | ((uint)f2b(v.y) << 16);
    p.y = (uint)f2b(v.z) | ((uint)f2b(v.w) << 16);
    *(uint2*)&As[(b * 18 + tau + 1) * XR + c4i * 4] = p;
  }
  __syncthreads();

  // conv GEMM, 2-slot software pipeline: wave w owns batches 2w, 2w+1
  f32x4 acc[2][8];
  #pragma unroll
  for (int bb = 0; bb < 2; ++bb)
    #pragma unroll
    for (int nt = 0; nt < 8; ++nt) {
      float bv = b1[nt * 16 + m];
      acc[bb][nt] = (f32x4){bv, bv, bv, bv};
    }
  int b0 = 2 * w;

  ABu a0[2], a1[2];
  bf16x8 bfr[2][8];
  auto LOADA = [&](int s, int slot) {
    int kk = s >> 1, sp = s & 1;
    int col = 32 * sp + 4 * g4;
    int r0 = (b0 * 18 + m + kk) * XR + col;
    int r1 = r0 + 18 * XR;
    a0[slot].u2[0] = *(const uint2*)&As[r0];
    a0[slot].u2[1] = *(const uint2*)&As[r0 + 16];
    a1[slot].u2[0] = *(const uint2*)&As[r1];
    a1[slot].u2[1] = *(const uint2*)&As[r1 + 16];
  };
  auto LOADB = [&](int s, int slot) {
    #pragma unroll
    for (int nt = 0; nt < 8; ++nt)
      bfr[slot][nt] = *(const bf16x8*)&Bp1[((s * 8 + nt) * 64 + l) * 8];
  };
  LOADA(0, 0);
  LOADB(0, 0);
  #pragma unroll
  for (int s = 0; s < 6; ++s) {
    const int cur = s & 1, nxt = cur ^ 1;
    if (s < 5) { LOADA(s + 1, nxt); LOADB(s + 1, nxt); }
    #pragma unroll
    for (int nt = 0; nt < 8; ++nt) {
      acc[0][nt] = __builtin_amdgcn_mfma_f32_16x16x32_bf16(a0[cur].v, bfr[cur][nt], acc[0][nt], 0, 0, 0);
      acc[1][nt] = __builtin_amdgcn_mfma_f32_16x16x32_bf16(a1[cur].v, bfr[cur][nt], acc[1][nt], 0, 0, 0);
    }
  }

  // prefetch linear-B frags, then GLU epilogue -> hs in own batches' rows (wave-private)
  bf16x8 wl[8];
  #pragma unroll
  for (int q = 0; q < 8; ++q)
    wl[q] = *(const bf16x8*)&Wgp[(q * 64 + l) * 8];

  #pragma unroll
  for (int bb = 0; bb < 2; ++bb) {
    int b = b0 + bb;
    #pragma unroll
    for (int nt = 0; nt < 4; ++nt)
      #pragma unroll
      for (int i = 0; i < 4; ++i) {
        float v = acc[bb][nt][i], gt = acc[bb][nt + 4][i];
        float h = fmaxf(v / (1.f + __expf(-gt)), 0.f);
        int t = 4 * g4 + i;
        As[(b * 18 + t + 1) * XR + nt * 16 + m] = f2b(h);
      }
  }

  // linear GEMM: y = h @ Wg^T + bg
  f32x4 acc2[2][4];
  #pragma unroll
  for (int bb = 0; bb < 2; ++bb)
    #pragma unroll
    for (int nt = 0; nt < 4; ++nt) {
      float bv = bg[nt * 16 + m];
      acc2[bb][nt] = (f32x4){bv, bv, bv, bv};
    }
  #pragma unroll
  for (int s2 = 0; s2 < 2; ++s2) {
    #pragma unroll
    for (int bb = 0; bb < 2; ++bb) {
      int b = b0 + bb;
      int rb = (b * 18 + m + 1) * XR + 32 * s2 + 4 * g4;
      ABu a;
      a.u2[0] = *(const uint2*)&As[rb];
      a.u2[1] = *(const uint2*)&As[rb + 16];
      #pragma unroll
      for (int nt = 0; nt < 4; ++nt) {
        acc2[bb][nt] = __builtin_amdgcn_mfma_f32_16x16x32_bf16(a.v, wl[s2 * 4 + nt], acc2[bb][nt], 0, 0, 0);
      }
    }
  }
  // store y (bf16, node-major [n][b][t][c])
  #pragma unroll
  for (int bb = 0; bb < 2; ++bb) {
    int b = b0 + bb;
    ushort* yb = y + ((size_t)n * NB + b) * 1024;
    #pragma unroll
    for (int nt = 0; nt < 4; ++nt)
      #pragma unroll
      for (int i = 0; i < 4; ++i) {
        int t = 4 * g4 + i;
        yb[t * 64 + nt * 16 + m] = f2b(acc2[bb][nt][i]);
      }
  }
}

// ---------------- CSR gather (weighted sum over edges) + ReLU, bf16 ----------------
__global__ __launch_bounds__(256) void k_gather(
    const ushort* __restrict__ y, const int* __restrict__ offsets,
    const int* __restrict__ esort, const int* __restrict__ edge_dst,
    const float* __restrict__ ew, ushort* __restrict__ agg) {
  int tid = threadIdx.x;
  int blk = blockIdx.x;
  int n = blk >> 1, s = blk & 1;
  int base = s * 2048 + tid * 8;
  int e0 = offsets[n], e1 = offsets[n + 1];

  float a0 = 0, a1 = 0, a2 = 0, a3 = 0, a4 = 0, a5 = 0, a6 = 0, a7 = 0;
  int e = e0;
  for (; e + 2 <= e1; e += 2) {
    int eid0 = esort[e], eid1 = esort[e + 1];
    int d0 = edge_dst[eid0], d1 = edge_dst[eid1];
    float w0 = ew[eid0], w1 = ew[eid1];
    uint4 v0 = *(const uint4*)(y + (size_t)d0 * 4096 + base);
    uint4 v1 = *(const uint4*)(y + (size_t)d1 * 4096 + base);
    a0 += w0 * blo(v0.x); a1 += w0 * bhi(v0.x);
    a2 += w0 * blo(v0.y); a3 += w0 * bhi(v0.y);
    a4 += w0 * blo(v0.z); a5 += w0 * bhi(v0.z);
    a6 += w0 * blo(v0.w); a7 += w0 * bhi(v0.w);
    a0 += w1 * blo(v1.x); a1 += w1 * bhi(v1.x);
    a2 += w1 * blo(v1.y); a3 += w1 * bhi(v1.y);
    a4 += w1 * blo(v1.z); a5 += w1 * bhi(v1.z);
    a6 += w1 * blo(v1.w); a7 += w1 * bhi(v1.w);
  }
  if (e < e1) {
    int eid0 = esort[e];
    int d0 = edge_dst[eid0];
    float w0 = ew[eid0];
    uint4 v0 = *(const uint4*)(y + (size_t)d0 * 4096 + base);
    a0 += w0 * blo(v0.x); a1 += w0 * bhi(v0.x);
    a2 += w0 * blo(v0.y); a3 += w0 * bhi(v0.y);
    a4 += w0 * blo(v0.z); a5 += w0 * bhi(v0.z);
    a6 += w0 * blo(v0.w); a7 += w0 * bhi(v0.w);
  }
  uint4 o;
  o.x = (uint)f2b(fmaxf(a0, 0.f)) | ((uint)f2b(fmaxf(a1, 0.f)) << 16);
  o.y = (uint)f2b(fmaxf(a2, 0.f)) | ((uint)f2b(fmaxf(a3, 0.f)) << 16);
  o.z = (uint)f2b(fmaxf(a4, 0.f)) | ((uint)f2b(fmaxf(a5, 0.f)) << 16);
  o.w = (uint)f2b(fmaxf(a6, 0.f)) | ((uint)f2b(fmaxf(a7, 0.f)) << 16);
  *(uint4*)(agg + (size_t)n * 4096 + base) = o;
}

// ---------------- GLU2(MFMA) + residual + per-block stats ----------------
__global__ __launch_bounds__(128, 2) void k_glu2(
    const ushort* __restrict__ agg, const float* __restrict__ x,
    const ushort* __restrict__ Bp2, const float* __restrict__ b2,
    float* __restrict__ out, float* __restrict__ partials) {
  __shared__ ushort As[4 * 18 * XR];   // 10368 B; reused as red[] after conv
  int tid = threadIdx.x;
  int n = blockIdx.x;
  int w = tid >> 6, l = tid & 63, m = l & 15, g4 = l >> 4;

  {
    int strip = tid >> 4, b = strip >> 1, tp = (strip & 1) ? 17 : 0;
    int c4 = (tid & 15) * 4;
    *(uint2*)&As[(b * 18 + tp) * XR + c4] = make_uint2(0, 0);
  }
  const uint4* ag4 = (const uint4*)(agg + (size_t)n * 4096);
  #pragma unroll
  for (int q = 0; q < 4; ++q) {
    int u = q * 128 + tid;
    uint4 v = ag4[u];
    int b = u >> 7, rem = u & 127, tau = rem >> 3, c0 = (rem & 7) * 8;
    *(uint4*)&As[(b * 18 + tau + 1) * XR + c0] = v;
  }
  // prefetch residual x (consumed in epilogue); waits fold into the barrier drain
  int b0 = 2 * w;
  float xr[2][4][4];
  #pragma unroll
  for (int bb = 0; bb < 2; ++bb) {
    const float* xb = x + ((size_t)(b0 + bb) * NN + n) * 1024 + m;
    #pragma unroll
    for (int nt = 0; nt < 4; ++nt)
      #pragma unroll
      for (int i = 0; i < 4; ++i)
        xr[bb][nt][i] = xb[(4 * g4 + i) * 64 + nt * 16];
  }
  __syncthreads();

  f32x4 acc[2][8];
  #pragma unroll
  for (int bb = 0; bb < 2; ++bb)
    #pragma unroll
    for (int nt = 0; nt < 8; ++nt) {
      float bv = b2[nt * 16 + m];
      acc[bb][nt] = (f32x4){bv, bv, bv, bv};
    }

  ABu a0[2], a1[2];
  bf16x8 bfr[2][8];
  auto LOADA = [&](int s, int slot) {
    int kk = s >> 1, sp = s & 1;
    int col = 32 * sp + 4 * g4;
    int r0 = (b0 * 18 + m + kk) * XR + col;
    int r1 = r0 + 18 * XR;
    a0[slot].u2[0] = *(const uint2*)&As[r0];
    a0[slot].u2[1] = *(const uint2*)&As[r0 + 16];
    a1[slot].u2[0] = *(const uint2*)&As[r1];
    a1[slot].u2[1] = *(const uint2*)&As[r1 + 16];
  };
  auto LOADB = [&](int s, int slot) {
    #pragma unroll
    for (int nt = 0; nt < 8; ++nt)
      bfr[slot][nt] = *(const bf16x8*)&Bp2[((s * 8 + nt) * 64 + l) * 8];
  };
  LOADA(0, 0);
  LOADB(0, 0);
  #pragma unroll
  for (int s = 0; s < 6; ++s) {
    const int cur = s & 1, nxt = cur ^ 1;
    if (s < 5) { LOADA(s + 1, nxt); LOADB(s + 1, nxt); }
    #pragma unroll
    for (int nt = 0; nt < 8; ++nt) {
      acc[0][nt] = __builtin_amdgcn_mfma_f32_16x16x32_bf16(a0[cur].v, bfr[cur][nt], acc[0][nt], 0, 0, 0);
      acc[1][nt] = __builtin_amdgcn_mfma_f32_16x16x32_bf16(a1[cur].v, bfr[cur][nt], acc[1][nt], 0, 0, 0);
    }
  }
  __syncthreads();  // As dead; reuse as float red[2][8][68]

  float* red = (float*)As;
  float p1[4] = {0, 0, 0, 0}, p2[4] = {0, 0, 0, 0};
  #pragma unroll
  for (int bb = 0; bb < 2; ++bb) {
    int b = b0 + bb;
    #pragma unroll
    for (int nt = 0; nt < 4; ++nt)
      #pragma unroll
      for (int i = 0; i < 4; ++i) {
        float v = acc[bb][nt][i], gt = acc[bb][nt + 4][i];
        float h = v / (1.f + __expf(-gt));
        int t = 4 * g4 + i;
        int idx = ((b * NN + n) * 16 + t) * 64 + nt * 16 + m;
        float res = h + xr[bb][nt][i];
        out[idx] = res;
        p1[nt] += res;
        p2[nt] += res * res;
      }
  }
  int rr = w * 4 + g4;
  #pragma unroll
  for (int nt = 0; nt < 4; ++nt) {
    red[rr * 68 + nt * 16 + m] = p1[nt];
    red[544 + rr * 68 + nt * 16 + m] = p2[nt];
  }
  __syncthreads();
  if (tid < 64) {
    float s = 0;
    #pragma unroll
    for (int r2 = 0; r2 < 8; ++r2) s += red[r2 * 68 + tid];
    partials[tid * NN + n] = s;
  } else {
    int c = tid - 64;
    float s = 0;
    #pragma unroll
    for (int r2 = 0; r2 < 8; ++r2) s += red[544 + r2 * 68 + c];
    partials[(64 + c) * NN + n] = s;
  }
}

// ---------------- reduce partials -> chan[128] ----------------
__global__ __launch_bounds__(256) void k_reduce(const float* __restrict__ partials,
                                                float* __restrict__ chan) {
  __shared__ float sm[256];
  int r = blockIdx.x, tid = threadIdx.x;
  const float* p = partials + (size_t)r * NN;
  float s = 0.f;
  for (int i = tid; i < NN; i += 256) s += p[i];
  sm[tid] = s;
  __syncthreads();
  for (int w = 128; w >= 1; w >>= 1) {
    if (tid < w) sm[tid] += sm[tid + w];
    __syncthreads();
  }
  if (tid == 0) chan[r] = sm[0];
}

// ---------------- layernorm (global per-channel stats) + relu, in place ----------------
__global__ __launch_bounds__(256) void k_norm(
    float* __restrict__ out, const float* __restrict__ chan,
    const float* __restrict__ gamma, const float* __restrict__ beta) {
  __shared__ float sc[64], sh[64];
  int tid = threadIdx.x;
  if (tid < 64) {
    const float inv = 1.f / (float)(NB * NN * NT);
    float mean = chan[tid] * inv;
    float var = chan[64 + tid] * inv - mean * mean;
    float s = rsqrtf(var + 1e-5f) * gamma[tid];
    sc[tid] = s;
    sh[tid] = beta[tid] - mean * s;
  }
  __syncthreads();
  float4* o4 = (float4*)out;
  const int total = NB * NN * NT * 16;
  for (int i = blockIdx.x * blockDim.x + threadIdx.x; i < total;
       i += gridDim.x * blockDim.x) {
    float4 v = o4[i];
    int c = (i * 4) & 63;
    v.x = fmaxf(v.x * sc[c + 0] + sh[c + 0], 0.f);
    v.y = fmaxf(v.y * sc[c + 1] + sh[c + 1], 0.f);
    v.z = fmaxf(v.z * sc[c + 2] + sh[c + 2], 0.f);
    v.w = fmaxf(v.w * sc[c + 3] + sh[c + 3], 0.f);
    o4[i] = v;
  }
}

// ---------------- launch ----------------

extern "C" void kernel_launch(void* const* d_in, const int* in_sizes, int n_in,
                              void* d_out, int out_size, void* d_ws, size_t ws_size,
                              hipStream_t stream) {
  const float* x    = (const float*)d_in[0];
  const int* esrc   = (const int*)d_in[1];
  const int* edst   = (const int*)d_in[2];
  const float* ew   = (const float*)d_in[3];
  const float* W1   = (const float*)d_in[4];
  const float* b1   = (const float*)d_in[5];
  const float* Wg   = (const float*)d_in[6];
  const float* bg   = (const float*)d_in[7];
  const float* W2   = (const float*)d_in[8];
  const float* b2   = (const float*)d_in[9];
  const float* gamma = (const float*)d_in[10];
  const float* beta  = (const float*)d_in[11];
  float* out = (float*)d_out;

  ushort* y_bf   = (ushort*)d_ws;          // 16777216 bf16 (node-major); dead after gather
  ushort* agg_bf = y_bf + 16777216;        // 16777216 bf16 (node-major)
  ushort* Bp1    = agg_bf + 16777216;      // 24576
  ushort* Bp2    = Bp1 + 24576;            // 24576
  ushort* Wgp    = Bp2 + 24576;            // 4096
  float* chan    = (float*)(Wgp + 4096);   // 128
  int* count   = (int*)(chan + 128);       // 4096
  int* offsets = count + 4096;             // 4097
  int* cursor  = offsets + 4097;           // 4096
  int* esort   = cursor + 4096;            // 32768
  float* partials = (float*)y_bf;          // 128*4096 floats, aliases dead y

  hipLaunchKernelGGL(k_prep, dim3(128), dim3(256), 0, stream, W1, W2, Wg, Bp1, Bp2, Wgp, count);
  hipLaunchKernelGGL(k_count, dim3(128), dim3(256), 0, stream, esrc, count);
  hipLaunchKernelGGL(k_scan, dim3(1), dim3(256), 0, stream, count, offsets, cursor);
  hipLaunchKernelGGL(k_place, dim3(128), dim3(256), 0, stream, esrc, cursor, esort);
  hipLaunchKernelGGL(k_glu1lin, dim3(NN), dim3(128), 0, stream,
                     x, Bp1, b1, Wgp, bg, y_bf);
  hipLaunchKernelGGL(k_gather, dim3(NN * 2), dim3(256), 0, stream,
                     y_bf, offsets, esort, edst, ew, agg_bf);
  hipLaunchKernelGGL(k_glu2, dim3(NN), dim3(128), 0, stream,
                     agg_bf, x, Bp2, b2, out, partials);
  hipLaunchKernelGGL(k_reduce, dim3(128), dim3(256), 0, stream, partials, chan);
  hipLaunchKernelGGL(k_norm, dim3(2048), dim3(256), 0, stream,
                     out, chan, gamma, beta);
}

// Round 8
// 176.067 us; speedup vs baseline: 1.0028x; 1.0028x over previous
//
#include <hip/hip_runtime.h>

#define NB 4
#define NN 4096
#define NT 16
#define NC 64
#define NE 32768
#define XR 72   // LDS tile row stride (bf16 elems); 144B = 16B-aligned, bank-spread

typedef unsigned int uint;
typedef unsigned short ushort;

typedef short bf16x8 __attribute__((ext_vector_type(8)));
typedef float f32x4 __attribute__((ext_vector_type(4)));

union ABu { uint2 u2[2]; bf16x8 v; };

__device__ inline ushort f2b(float f) {
  union { float f; uint u; } v; v.f = f;
  uint r = v.u + 0x7FFF + ((v.u >> 16) & 1);
  return (ushort)(r >> 16);
}
__device__ inline float blo(uint u) { union { uint i; float f; } v; v.i = u << 16; return v.f; }
__device__ inline float bhi(uint u) { union { uint i; float f; } v; v.i = u & 0xffff0000u; return v.f; }

// ---------------- prep: weight packing + count zeroing (merged) ----------------
// Bpack fragment layout (bf16): Bp[(((s*8+nt)*64+l)*8)+j] = B[kappa][o]
//   kappa = 32s + 4*(l>>4) + (j&3) + 16*(j>>2), o = nt*16 + (l&15)
//   conv B: B[c + 64*kk][o] = W[o,c,kk];  linear B: B[c][d] = Wg[d,c]
__global__ void k_prep(const float* __restrict__ W1, const float* __restrict__ W2,
                       const float* __restrict__ Wg,
                       ushort* __restrict__ Bp1, ushort* __restrict__ Bp2,
                       ushort* __restrict__ Wgp, int* __restrict__ count) {
  int i = blockIdx.x * blockDim.x + threadIdx.x;
  if (i < 24576) {
    int j = i & 7, l = (i >> 3) & 63, nt = (i >> 9) & 7, s = i >> 12;
    int kap = 32 * s + 4 * (l >> 4) + (j & 3) + 16 * (j >> 2);
    int c = kap & 63, kk = kap >> 6, o = nt * 16 + (l & 15);
    Bp1[i] = f2b(W1[o * 192 + c * 3 + kk]);
    Bp2[i] = f2b(W2[o * 192 + c * 3 + kk]);
  } else if (i < 28672) {
    int i2 = i - 24576;
    int j = i2 & 7, l = (i2 >> 3) & 63, nt2 = (i2 >> 9) & 3, s2 = i2 >> 11;
    int kap = 32 * s2 + 4 * (l >> 4) + (j & 3) + 16 * (j >> 2);
    int d = nt2 * 16 + (l & 15);
    Wgp[i2] = f2b(Wg[d * 64 + kap]);
  } else {
    count[i - 28672] = 0;
  }
}

__global__ void k_count(const int* __restrict__ src, int* __restrict__ count) {
  int e = blockIdx.x * blockDim.x + threadIdx.x;
  if (e < NE) atomicAdd(&count[src[e]], 1);
}

__global__ void k_scan(const int* __restrict__ count, int* __restrict__ offsets,
                       int* __restrict__ cursor) {
  __shared__ int part[256];
  int tid = threadIdx.x;
  int base = tid * 16;
  int s = 0;
  for (int i = 0; i < 16; ++i) s += count[base + i];
  part[tid] = s;
  __syncthreads();
  if (tid == 0) {
    int r = 0;
    for (int i = 0; i < 256; ++i) { int t = part[i]; part[i] = r; r += t; }
    offsets[NN] = r;
  }
  __syncthreads();
  int r = part[tid];
  for (int i = 0; i < 16; ++i) {
    offsets[base + i] = r;
    cursor[base + i] = r;
    r += count[base + i];
  }
}

// place: also pre-gather dst and weight into sorted order (kills one dependent
// load level in k_gather: esort[e] -> edge_dst[eid]/ew[eid] becomes direct).
__global__ void k_place(const int* __restrict__ src, const int* __restrict__ dst,
                        const float* __restrict__ ew, int* __restrict__ cursor,
                        int* __restrict__ dsts, float* __restrict__ wsrt) {
  int e = blockIdx.x * blockDim.x + threadIdx.x;
  if (e < NE) {
    int p = atomicAdd(&cursor[src[e]], 1);
    dsts[p] = dst[e];
    wsrt[p] = ew[e];
  }
}

// ---------------- GLU1(MFMA) + GCN-linear(MFMA): 1 node/block, 4 waves ----------------
// Wave w owns batch w -> acc[8] = 32 AGPR/wave (unified-file footprint is the
// occupancy limiter: R7 measured 72 VGPR + 64 AGPR -> 3 waves/SIMD, 26% occ).
// Compact tile Xs[b][tp][c], tp=t+1 (rows 0,17 zero); conv expansion at read time.
__global__ __launch_bounds__(256, 3) void k_glu1lin(
    const float* __restrict__ x, const ushort* __restrict__ Bp1,
    const float* __restrict__ b1, const ushort* __restrict__ Wgp,
    const float* __restrict__ bg, ushort* __restrict__ y) {
  __shared__ ushort As[4 * 18 * XR];   // 10368 B
  int tid = threadIdx.x;
  int n = blockIdx.x;
  int w = tid >> 6, l = tid & 63, m = l & 15, g4 = l >> 4;

  // zero pad rows tp=0,17 per batch (128 strips)
  if (tid < 128) {
    int b = tid >> 5, tp = ((tid >> 4) & 1) ? 17 : 0, c4 = (tid & 15) * 4;
    *(uint2*)&As[(b * 18 + tp) * XR + c4] = make_uint2(0, 0);
  }
  // stage x -> compact bf16 tile (1024 float4, coalesced)
  const float4* x4 = (const float4*)x;
  #pragma unroll
  for (int q = 0; q < 4; ++q) {
    int f4 = q * 256 + tid;
    int b = f4 >> 8, rem = f4 & 255, tau = rem >> 4, c4i = rem & 15;
    float4 v = x4[((b * NN + n) * 16 + tau) * 16 + c4i];
    uint2 p;
    p.x = (uint)f2b(v.x) | ((uint)f2b(v.y) << 16);
    p.y = (uint)f2b(v.z) | ((uint)f2b(v.w) << 16);
    *(uint2*)&As[(b * 18 + tau + 1) * XR + c4i * 4] = p;
  }
  __syncthreads();

  // conv GEMM: wave w owns batch w
  f32x4 acc[8];
  #pragma unroll
  for (int nt = 0; nt < 8; ++nt) {
    float bv = b1[nt * 16 + m];
    acc[nt] = (f32x4){bv, bv, bv, bv};
  }
  #pragma unroll
  for (int s = 0; s < 6; ++s) {
    const int kk = s >> 1, sp = s & 1;
    int r0 = (w * 18 + m + kk) * XR + 32 * sp + 4 * g4;
    ABu a;
    a.u2[0] = *(const uint2*)&As[r0];
    a.u2[1] = *(const uint2*)&As[r0 + 16];
    #pragma unroll
    for (int nt = 0; nt < 8; ++nt) {
      bf16x8 bf = *(const bf16x8*)&Bp1[((s * 8 + nt) * 64 + l) * 8];
      acc[nt] = __builtin_amdgcn_mfma_f32_16x16x32_bf16(a.v, bf, acc[nt], 0, 0, 0);
    }
  }

  // GLU epilogue -> hs in own batch rows (wave-private; no barrier needed)
  #pragma unroll
  for (int nt = 0; nt < 4; ++nt)
    #pragma unroll
    for (int i = 0; i < 4; ++i) {
      float v = acc[nt][i], gt = acc[nt + 4][i];
      float h = fmaxf(v / (1.f + __expf(-gt)), 0.f);
      int t = 4 * g4 + i;
      As[(w * 18 + t + 1) * XR + nt * 16 + m] = f2b(h);
    }

  // linear GEMM: y = h @ Wg^T + bg (reads only own batch rows)
  f32x4 acc2[4];
  #pragma unroll
  for (int nt = 0; nt < 4; ++nt) {
    float bv = bg[nt * 16 + m];
    acc2[nt] = (f32x4){bv, bv, bv, bv};
  }
  #pragma unroll
  for (int s2 = 0; s2 < 2; ++s2) {
    int rb = (w * 18 + m + 1) * XR + 32 * s2 + 4 * g4;
    ABu a;
    a.u2[0] = *(const uint2*)&As[rb];
    a.u2[1] = *(const uint2*)&As[rb + 16];
    #pragma unroll
    for (int nt = 0; nt < 4; ++nt) {
      bf16x8 bf = *(const bf16x8*)&Wgp[((s2 * 4 + nt) * 64 + l) * 8];
      acc2[nt] = __builtin_amdgcn_mfma_f32_16x16x32_bf16(a.v, bf, acc2[nt], 0, 0, 0);
    }
  }
  // store y (bf16, node-major [n][b][t][c])
  ushort* yb = y + ((size_t)n * NB + w) * 1024;
  #pragma unroll
  for (int nt = 0; nt < 4; ++nt)
    #pragma unroll
    for (int i = 0; i < 4; ++i) {
      int t = 4 * g4 + i;
      yb[t * 64 + nt * 16 + m] = f2b(acc2[nt][i]);
    }
}

// ---------------- CSR gather (weighted sum over edges) + ReLU, bf16 ----------------
__global__ __launch_bounds__(256) void k_gather(
    const ushort* __restrict__ y, const int* __restrict__ offsets,
    const int* __restrict__ dsts, const float* __restrict__ wsrt,
    ushort* __restrict__ agg) {
  int tid = threadIdx.x;
  int blk = blockIdx.x;
  int n = blk >> 1, s = blk & 1;
  int base = s * 2048 + tid * 8;
  int e0 = offsets[n], e1 = offsets[n + 1];

  float a0 = 0, a1 = 0, a2 = 0, a3 = 0, a4 = 0, a5 = 0, a6 = 0, a7 = 0;
  int e = e0;
  for (; e + 2 <= e1; e += 2) {
    int d0 = dsts[e], d1 = dsts[e + 1];
    float w0 = wsrt[e], w1 = wsrt[e + 1];
    uint4 v0 = *(const uint4*)(y + (size_t)d0 * 4096 + base);
    uint4 v1 = *(const uint4*)(y + (size_t)d1 * 4096 + base);
    a0 += w0 * blo(v0.x); a1 += w0 * bhi(v0.x);
    a2 += w0 * blo(v0.y); a3 += w0 * bhi(v0.y);
    a4 += w0 * blo(v0.z); a5 += w0 * bhi(v0.z);
    a6 += w0 * blo(v0.w); a7 += w0 * bhi(v0.w);
    a0 += w1 * blo(v1.x); a1 += w1 * bhi(v1.x);
    a2 += w1 * blo(v1.y); a3 += w1 * bhi(v1.y);
    a4 += w1 * blo(v1.z); a5 += w1 * bhi(v1.z);
    a6 += w1 * blo(v1.w); a7 += w1 * bhi(v1.w);
  }
  if (e < e1) {
    int d0 = dsts[e];
    float w0 = wsrt[e];
    uint4 v0 = *(const uint4*)(y + (size_t)d0 * 4096 + base);
    a0 += w0 * blo(v0.x); a1 += w0 * bhi(v0.x);
    a2 += w0 * blo(v0.y); a3 += w0 * bhi(v0.y);
    a4 += w0 * blo(v0.z); a5 += w0 * bhi(v0.z);
    a6 += w0 * blo(v0.w); a7 += w0 * bhi(v0.w);
  }
  uint4 o;
  o.x = (uint)f2b(fmaxf(a0, 0.f)) | ((uint)f2b(fmaxf(a1, 0.f)) << 16);
  o.y = (uint)f2b(fmaxf(a2, 0.f)) | ((uint)f2b(fmaxf(a3, 0.f)) << 16);
  o.z = (uint)f2b(fmaxf(a4, 0.f)) | ((uint)f2b(fmaxf(a5, 0.f)) << 16);
  o.w = (uint)f2b(fmaxf(a6, 0.f)) | ((uint)f2b(fmaxf(a7, 0.f)) << 16);
  *(uint4*)(agg + (size_t)n * 4096 + base) = o;
}

// ---------------- GLU2(MFMA) + residual + per-block stats ----------------
__global__ __launch_bounds__(256, 3) void k_glu2(
    const ushort* __restrict__ agg, const float* __restrict__ x,
    const ushort* __restrict__ Bp2, const float* __restrict__ b2,
    float* __restrict__ out, float* __restrict__ partials) {
  __shared__ ushort As[4 * 18 * XR];   // 10368 B; reused as red[] after conv
  int tid = threadIdx.x;
  int n = blockIdx.x;
  int w = tid >> 6, l = tid & 63, m = l & 15, g4 = l >> 4;

  if (tid < 128) {
    int b = tid >> 5, tp = ((tid >> 4) & 1) ? 17 : 0, c4 = (tid & 15) * 4;
    *(uint2*)&As[(b * 18 + tp) * XR + c4] = make_uint2(0, 0);
  }
  const uint4* ag4 = (const uint4*)(agg + (size_t)n * 4096);
  #pragma unroll
  for (int q = 0; q < 2; ++q) {
    int u = q * 256 + tid;
    uint4 v = ag4[u];
    int b = u >> 7, rem = u & 127, tau = rem >> 3, c0 = (rem & 7) * 8;
    *(uint4*)&As[(b * 18 + tau + 1) * XR + c0] = v;
  }
  __syncthreads();

  // issue residual x loads AFTER the barrier: they stay in flight across the
  // whole conv loop (no intervening barrier -> no vmcnt(0) drain; R7 lesson:
  // pre-barrier issue puts full HBM latency on the critical path).
  float xr[4][4];
  {
    const float* xb = x + ((size_t)w * NN + n) * 1024 + m;
    #pragma unroll
    for (int nt = 0; nt < 4; ++nt)
      #pragma unroll
      for (int i = 0; i < 4; ++i)
        xr[nt][i] = xb[(4 * g4 + i) * 64 + nt * 16];
  }

  f32x4 acc[8];
  #pragma unroll
  for (int nt = 0; nt < 8; ++nt) {
    float bv = b2[nt * 16 + m];
    acc[nt] = (f32x4){bv, bv, bv, bv};
  }
  #pragma unroll
  for (int s = 0; s < 6; ++s) {
    const int kk = s >> 1, sp = s & 1;
    int r0 = (w * 18 + m + kk) * XR + 32 * sp + 4 * g4;
    ABu a;
    a.u2[0] = *(const uint2*)&As[r0];
    a.u2[1] = *(const uint2*)&As[r0 + 16];
    #pragma unroll
    for (int nt = 0; nt < 8; ++nt) {
      bf16x8 bf = *(const bf16x8*)&Bp2[((s * 8 + nt) * 64 + l) * 8];
      acc[nt] = __builtin_amdgcn_mfma_f32_16x16x32_bf16(a.v, bf, acc[nt], 0, 0, 0);
    }
  }

  // epilogue: GLU + residual + out store + per-thread stats (registers only)
  float p1[4] = {0, 0, 0, 0}, p2[4] = {0, 0, 0, 0};
  #pragma unroll
  for (int nt = 0; nt < 4; ++nt)
    #pragma unroll
    for (int i = 0; i < 4; ++i) {
      float v = acc[nt][i], gt = acc[nt + 4][i];
      float h = v / (1.f + __expf(-gt));
      int t = 4 * g4 + i;
      int idx = ((w * NN + n) * 16 + t) * 64 + nt * 16 + m;
      float res = h + xr[nt][i];
      out[idx] = res;
      p1[nt] += res;
      p2[nt] += res * res;
    }
  __syncthreads();  // all waves done reading As -> safe to reuse as red

  // red: sum rows [0..16), sumsq rows at +1088 floats; row = w*4+g4, 68-stride
  float* red = (float*)As;
  int rr = w * 4 + g4;
  #pragma unroll
  for (int nt = 0; nt < 4; ++nt) {
    red[rr * 68 + nt * 16 + m] = p1[nt];
    red[1088 + rr * 68 + nt * 16 + m] = p2[nt];
  }
  __syncthreads();
  if (tid < 64) {
    float s = 0;
    #pragma unroll
    for (int r2 = 0; r2 < 16; ++r2) s += red[r2 * 68 + tid];
    partials[tid * NN + n] = s;
  } else if (tid < 128) {
    int c = tid - 64;
    float s = 0;
    #pragma unroll
    for (int r2 = 0; r2 < 16; ++r2) s += red[1088 + r2 * 68 + c];
    partials[(64 + c) * NN + n] = s;
  }
}

// ---------------- reduce partials -> chan[128] ----------------
__global__ __launch_bounds__(256) void k_reduce(const float* __restrict__ partials,
                                                float* __restrict__ chan) {
  __shared__ float sm[256];
  int r = blockIdx.x, tid = threadIdx.x;
  const float* p = partials + (size_t)r * NN;
  float s = 0.f;
  for (int i = tid; i < NN; i += 256) s += p[i];
  sm[tid] = s;
  __syncthreads();
  for (int w = 128; w >= 1; w >>= 1) {
    if (tid < w) sm[tid] += sm[tid + w];
    __syncthreads();
  }
  if (tid == 0) chan[r] = sm[0];
}

// ---------------- layernorm (global per-channel stats) + relu, in place ----------------
__global__ __launch_bounds__(256) void k_norm(
    float* __restrict__ out, const float* __restrict__ chan,
    const float* __restrict__ gamma, const float* __restrict__ beta) {
  __shared__ float sc[64], sh[64];
  int tid = threadIdx.x;
  if (tid < 64) {
    const float inv = 1.f / (float)(NB * NN * NT);
    float mean = chan[tid] * inv;
    float var = chan[64 + tid] * inv - mean * mean;
    float s = rsqrtf(var + 1e-5f) * gamma[tid];
    sc[tid] = s;
    sh[tid] = beta[tid] - mean * s;
  }
  __syncthreads();
  float4* o4 = (float4*)out;
  const int total = NB * NN * NT * 16;
  for (int i = blockIdx.x * blockDim.x + threadIdx.x; i < total;
       i += gridDim.x * blockDim.x) {
    float4 v = o4[i];
    int c = (i * 4) & 63;
    v.x = fmaxf(v.x * sc[c + 0] + sh[c + 0], 0.f);
    v.y = fmaxf(v.y * sc[c + 1] + sh[c + 1], 0.f);
    v.z = fmaxf(v.z * sc[c + 2] + sh[c + 2], 0.f);
    v.w = fmaxf(v.w * sc[c + 3] + sh[c + 3], 0.f);
    o4[i] = v;
  }
}

// ---------------- launch ----------------

extern "C" void kernel_launch(void* const* d_in, const int* in_sizes, int n_in,
                              void* d_out, int out_size, void* d_ws, size_t ws_size,
                              hipStream_t stream) {
  const float* x    = (const float*)d_in[0];
  const int* esrc   = (const int*)d_in[1];
  const int* edst   = (const int*)d_in[2];
  const float* ew   = (const float*)d_in[3];
  const float* W1   = (const float*)d_in[4];
  const float* b1   = (const float*)d_in[5];
  const float* Wg   = (const float*)d_in[6];
  const float* bg   = (const float*)d_in[7];
  const float* W2   = (const float*)d_in[8];
  const float* b2   = (const float*)d_in[9];
  const float* gamma = (const float*)d_in[10];
  const float* beta  = (const float*)d_in[11];
  float* out = (float*)d_out;

  ushort* y_bf   = (ushort*)d_ws;          // 16777216 bf16 (node-major); dead after gather
  ushort* agg_bf = y_bf + 16777216;        // 16777216 bf16 (node-major)
  ushort* Bp1    = agg_bf + 16777216;      // 24576
  ushort* Bp2    = Bp1 + 24576;            // 24576
  ushort* Wgp    = Bp2 + 24576;            // 4096
  float* chan    = (float*)(Wgp + 4096);   // 128
  int* count   = (int*)(chan + 128);       // 4096
  int* offsets = count + 4096;             // 4097
  int* cursor  = offsets + 4097;           // 4096
  int* dsts    = cursor + 4096;            // 32768 (pre-sorted edge dst)
  float* wsrt  = (float*)(dsts + NE);      // 32768 (pre-sorted edge weight)
  float* partials = (float*)y_bf;          // 128*4096 floats, aliases dead y

  hipLaunchKernelGGL(k_prep, dim3(128), dim3(256), 0, stream, W1, W2, Wg, Bp1, Bp2, Wgp, count);
  hipLaunchKernelGGL(k_count, dim3(128), dim3(256), 0, stream, esrc, count);
  hipLaunchKernelGGL(k_scan, dim3(1), dim3(256), 0, stream, count, offsets, cursor);
  hipLaunchKernelGGL(k_place, dim3(128), dim3(256), 0, stream, esrc, edst, ew, cursor, dsts, wsrt);
  hipLaunchKernelGGL(k_glu1lin, dim3(NN), dim3(256), 0, stream,
                     x, Bp1, b1, Wgp, bg, y_bf);
  hipLaunchKernelGGL(k_gather, dim3(NN * 2), dim3(256), 0, stream,
                     y_bf, offsets, dsts, wsrt, agg_bf);
  hipLaunchKernelGGL(k_glu2, dim3(NN), dim3(256), 0, stream,
                     agg_bf, x, Bp2, b2, out, partials);
  hipLaunchKernelGGL(k_reduce, dim3(128), dim3(256), 0, stream, partials, chan);
  hipLaunchKernelGGL(k_norm, dim3(2048), dim3(256), 0, stream,
                     out, chan, gamma, beta);
}

// Round 9
// 141.743 us; speedup vs baseline: 1.2456x; 1.2422x over previous
//
#include <hip/hip_runtime.h>

#define NB 4
#define NN 4096
#define NT 16
#define NC 64
#define NE 32768
#define XR 72    // LDS tile row stride (bf16 elems); 144B = 16B-aligned, bank-spread
#define MPB 2    // nodes per block (GLU kernels)

typedef unsigned int uint;
typedef unsigned short ushort;

typedef short bf16x8 __attribute__((ext_vector_type(8)));
typedef float f32x4 __attribute__((ext_vector_type(4)));

union ABu { uint2 u2[2]; bf16x8 v; };

__device__ inline ushort f2b(float f) {
  union { float f; uint u; } v; v.f = f;
  uint r = v.u + 0x7FFF + ((v.u >> 16) & 1);
  return (ushort)(r >> 16);
}
__device__ inline float blo(uint u) { union { uint i; float f; } v; v.i = u << 16; return v.f; }
__device__ inline float bhi(uint u) { union { uint i; float f; } v; v.i = u & 0xffff0000u; return v.f; }

// ---------------- prep: weight packing + count zeroing (merged) ----------------
// Bpack fragment layout (bf16): Bp[(((s*8+nt)*64+l)*8)+j] = B[kappa][o]
//   kappa = 32s + 4*(l>>4) + (j&3) + 16*(j>>2), o = nt*16 + (l&15)
//   conv B: B[c + 64*kk][o] = W[o,c,kk];  linear B: B[c][d] = Wg[d,c]
__global__ void k_prep(const float* __restrict__ W1, const float* __restrict__ W2,
                       const float* __restrict__ Wg,
                       ushort* __restrict__ Bp1, ushort* __restrict__ Bp2,
                       ushort* __restrict__ Wgp, int* __restrict__ count) {
  int i = blockIdx.x * blockDim.x + threadIdx.x;
  if (i < 24576) {
    int j = i & 7, l = (i >> 3) & 63, nt = (i >> 9) & 7, s = i >> 12;
    int kap = 32 * s + 4 * (l >> 4) + (j & 3) + 16 * (j >> 2);
    int c = kap & 63, kk = kap >> 6, o = nt * 16 + (l & 15);
    Bp1[i] = f2b(W1[o * 192 + c * 3 + kk]);
    Bp2[i] = f2b(W2[o * 192 + c * 3 + kk]);
  } else if (i < 28672) {
    int i2 = i - 24576;
    int j = i2 & 7, l = (i2 >> 3) & 63, nt2 = (i2 >> 9) & 3, s2 = i2 >> 11;
    int kap = 32 * s2 + 4 * (l >> 4) + (j & 3) + 16 * (j >> 2);
    int d = nt2 * 16 + (l & 15);
    Wgp[i2] = f2b(Wg[d * 64 + kap]);
  } else {
    count[i - 28672] = 0;
  }
}

__global__ void k_count(const int* __restrict__ src, int* __restrict__ count) {
  int e = blockIdx.x * blockDim.x + threadIdx.x;
  if (e < NE) atomicAdd(&count[src[e]], 1);
}

__global__ void k_scan(const int* __restrict__ count, int* __restrict__ offsets,
                       int* __restrict__ cursor) {
  __shared__ int part[256];
  int tid = threadIdx.x;
  int base = tid * 16;
  int s = 0;
  for (int i = 0; i < 16; ++i) s += count[base + i];
  part[tid] = s;
  __syncthreads();
  if (tid == 0) {
    int r = 0;
    for (int i = 0; i < 256; ++i) { int t = part[i]; part[i] = r; r += t; }
    offsets[NN] = r;
  }
  __syncthreads();
  int r = part[tid];
  for (int i = 0; i < 16; ++i) {
    offsets[base + i] = r;
    cursor[base + i] = r;
    r += count[base + i];
  }
}

__global__ void k_place(const int* __restrict__ src, const int* __restrict__ dst,
                        const float* __restrict__ ew, int* __restrict__ cursor,
                        int* __restrict__ dsts, float* __restrict__ wsrt) {
  int e = blockIdx.x * blockDim.x + threadIdx.x;
  if (e < NE) {
    int p = atomicAdd(&cursor[src[e]], 1);
    dsts[p] = dst[e];
    wsrt[p] = ew[e];
  }
}

// ---------------- GLU1(MFMA) + GCN-linear(MFMA): 2 nodes/block, 4 waves ----------------
// Wave w owns output col-tiles (w, w+4): value col o=16w+m and gate col o+64 stay
// in-lane -> in-register GLU. Conv B-frags (12) + Wg frags (2) live in registers,
// loaded ONCE per block (R8 lesson: per-node B re-load = 800MB L2 stream = the
// latency chain; MfmaUtil was stuck at 10% across 25-43% occupancy).
__global__ __launch_bounds__(256, 3) void k_glu1lin(
    const float* __restrict__ x, const ushort* __restrict__ Bp1,
    const float* __restrict__ b1, const ushort* __restrict__ Wgp,
    const float* __restrict__ bg, ushort* __restrict__ y) {
  __shared__ ushort As[MPB * 4 * 18 * XR + 64 * 68];  // tiles + hs; 29440 B
  ushort* hs = As + MPB * 4 * 18 * XR;
  int tid = threadIdx.x;
  int n0 = blockIdx.x * MPB;
  int w = tid >> 6, l = tid & 63, m = l & 15, g4 = l >> 4;

  // B fragments for this wave's col-pair, loaded once (in flight during staging)
  bf16x8 bc[6][2];
  #pragma unroll
  for (int s = 0; s < 6; ++s) {
    bc[s][0] = *(const bf16x8*)&Bp1[((s * 8 + w) * 64 + l) * 8];
    bc[s][1] = *(const bf16x8*)&Bp1[((s * 8 + w + 4) * 64 + l) * 8];
  }
  bf16x8 wg2[2];
  #pragma unroll
  for (int s2 = 0; s2 < 2; ++s2)
    wg2[s2] = *(const bf16x8*)&Wgp[((s2 * 4 + w) * 64 + l) * 8];

  // zero pad rows tp=0,17 per (node,batch)
  {
    int nd = tid >> 7, rem = tid & 127;
    int b = rem >> 5, tp = ((rem >> 4) & 1) ? 17 : 0, c4 = (rem & 15) * 4;
    *(uint2*)&As[((nd * 4 + b) * 18 + tp) * XR + c4] = make_uint2(0, 0);
  }
  // stage MPB node tiles -> compact bf16
  const float4* x4 = (const float4*)x;
  #pragma unroll
  for (int q = 0; q < 8; ++q) {
    int f4 = q * 256 + tid;
    int nd = f4 >> 10, rem = f4 & 1023;
    int b = rem >> 8, r = rem & 255, tau = r >> 4, c4i = r & 15;
    float4 v = x4[((b * NN + n0 + nd) * 16 + tau) * 16 + c4i];
    uint2 p;
    p.x = (uint)f2b(v.x) | ((uint)f2b(v.y) << 16);
    p.y = (uint)f2b(v.z) | ((uint)f2b(v.w) << 16);
    *(uint2*)&As[((nd * 4 + b) * 18 + tau + 1) * XR + c4i * 4] = p;
  }
  __syncthreads();

  float bv = b1[w * 16 + m], bgate = b1[64 + w * 16 + m];
  float bgl = bg[w * 16 + m];

  #pragma unroll
  for (int nd = 0; nd < MPB; ++nd) {
    int nd4 = nd * 4;
    // conv GEMM: acc[rt][ct], rt = batch, ct = {value, gate}
    f32x4 acc[4][2];
    #pragma unroll
    for (int rt = 0; rt < 4; ++rt) {
      acc[rt][0] = (f32x4){bv, bv, bv, bv};
      acc[rt][1] = (f32x4){bgate, bgate, bgate, bgate};
    }
    #pragma unroll
    for (int s = 0; s < 6; ++s) {
      const int kk = s >> 1, sp = s & 1;
      int col = 32 * sp + 4 * g4;
      #pragma unroll
      for (int rt = 0; rt < 4; ++rt) {
        int r0 = ((nd4 + rt) * 18 + m + kk) * XR + col;
        ABu a;
        a.u2[0] = *(const uint2*)&As[r0];
        a.u2[1] = *(const uint2*)&As[r0 + 16];
        acc[rt][0] = __builtin_amdgcn_mfma_f32_16x16x32_bf16(a.v, bc[s][0], acc[rt][0], 0, 0, 0);
        acc[rt][1] = __builtin_amdgcn_mfma_f32_16x16x32_bf16(a.v, bc[s][1], acc[rt][1], 0, 0, 0);
      }
    }
    // GLU -> hs (cols w*16..w*16+15 wave-private)
    #pragma unroll
    for (int rt = 0; rt < 4; ++rt)
      #pragma unroll
      for (int i = 0; i < 4; ++i) {
        float v = acc[rt][0][i], gt = acc[rt][1][i];
        float h = fmaxf(v / (1.f + __expf(-gt)), 0.f);
        hs[(rt * 16 + 4 * g4 + i) * 68 + w * 16 + m] = f2b(h);
      }
    __syncthreads();

    // linear GEMM: y[t][d], wave owns d-tile w
    f32x4 acc2[4];
    #pragma unroll
    for (int rt = 0; rt < 4; ++rt) acc2[rt] = (f32x4){bgl, bgl, bgl, bgl};
    #pragma unroll
    for (int s2 = 0; s2 < 2; ++s2) {
      #pragma unroll
      for (int rt = 0; rt < 4; ++rt) {
        int rb = (rt * 16 + m) * 68 + 32 * s2 + 4 * g4;
        ABu a;
        a.u2[0] = *(const uint2*)&hs[rb];
        a.u2[1] = *(const uint2*)&hs[rb + 16];
        acc2[rt] = __builtin_amdgcn_mfma_f32_16x16x32_bf16(a.v, wg2[s2], acc2[rt], 0, 0, 0);
      }
    }
    // store y (bf16, node-major [n][b][t][c])
    ushort* yb = y + ((size_t)(n0 + nd) * NB) * 1024;
    #pragma unroll
    for (int rt = 0; rt < 4; ++rt)
      #pragma unroll
      for (int i = 0; i < 4; ++i) {
        int t = 4 * g4 + i;
        yb[rt * 1024 + t * 64 + w * 16 + m] = f2b(acc2[rt][i]);
      }
    __syncthreads();  // hs reused by next node
  }
}

// ---------------- CSR gather (weighted sum over edges) + ReLU, bf16 ----------------
__global__ __launch_bounds__(256) void k_gather(
    const ushort* __restrict__ y, const int* __restrict__ offsets,
    const int* __restrict__ dsts, const float* __restrict__ wsrt,
    ushort* __restrict__ agg) {
  int tid = threadIdx.x;
  int blk = blockIdx.x;
  int n = blk >> 1, s = blk & 1;
  int base = s * 2048 + tid * 8;
  int e0 = offsets[n], e1 = offsets[n + 1];

  float a0 = 0, a1 = 0, a2 = 0, a3 = 0, a4 = 0, a5 = 0, a6 = 0, a7 = 0;
  int e = e0;
  for (; e + 2 <= e1; e += 2) {
    int d0 = dsts[e], d1 = dsts[e + 1];
    float w0 = wsrt[e], w1 = wsrt[e + 1];
    uint4 v0 = *(const uint4*)(y + (size_t)d0 * 4096 + base);
    uint4 v1 = *(const uint4*)(y + (size_t)d1 * 4096 + base);
    a0 += w0 * blo(v0.x); a1 += w0 * bhi(v0.x);
    a2 += w0 * blo(v0.y); a3 += w0 * bhi(v0.y);
    a4 += w0 * blo(v0.z); a5 += w0 * bhi(v0.z);
    a6 += w0 * blo(v0.w); a7 += w0 * bhi(v0.w);
    a0 += w1 * blo(v1.x); a1 += w1 * bhi(v1.x);
    a2 += w1 * blo(v1.y); a3 += w1 * bhi(v1.y);
    a4 += w1 * blo(v1.z); a5 += w1 * bhi(v1.z);
    a6 += w1 * blo(v1.w); a7 += w1 * bhi(v1.w);
  }
  if (e < e1) {
    int d0 = dsts[e];
    float w0 = wsrt[e];
    uint4 v0 = *(const uint4*)(y + (size_t)d0 * 4096 + base);
    a0 += w0 * blo(v0.x); a1 += w0 * bhi(v0.x);
    a2 += w0 * blo(v0.y); a3 += w0 * bhi(v0.y);
    a4 += w0 * blo(v0.z); a5 += w0 * bhi(v0.z);
    a6 += w0 * blo(v0.w); a7 += w0 * bhi(v0.w);
  }
  uint4 o;
  o.x = (uint)f2b(fmaxf(a0, 0.f)) | ((uint)f2b(fmaxf(a1, 0.f)) << 16);
  o.y = (uint)f2b(fmaxf(a2, 0.f)) | ((uint)f2b(fmaxf(a3, 0.f)) << 16);
  o.z = (uint)f2b(fmaxf(a4, 0.f)) | ((uint)f2b(fmaxf(a5, 0.f)) << 16);
  o.w = (uint)f2b(fmaxf(a6, 0.f)) | ((uint)f2b(fmaxf(a7, 0.f)) << 16);
  *(uint4*)(agg + (size_t)n * 4096 + base) = o;
}

// ---------------- GLU2(MFMA) + residual + stats: 2 nodes/block, 4 waves ----------------
__global__ __launch_bounds__(256, 3) void k_glu2(
    const ushort* __restrict__ agg, const float* __restrict__ x,
    const ushort* __restrict__ Bp2, const float* __restrict__ b2,
    float* __restrict__ out, float* __restrict__ partials) {
  __shared__ ushort As[MPB * 4 * 18 * XR];   // 20736 B
  __shared__ float red[512];
  int tid = threadIdx.x;
  int n0 = blockIdx.x * MPB;
  int w = tid >> 6, l = tid & 63, m = l & 15, g4 = l >> 4;

  bf16x8 bc[6][2];
  #pragma unroll
  for (int s = 0; s < 6; ++s) {
    bc[s][0] = *(const bf16x8*)&Bp2[((s * 8 + w) * 64 + l) * 8];
    bc[s][1] = *(const bf16x8*)&Bp2[((s * 8 + w + 4) * 64 + l) * 8];
  }

  {
    int nd = tid >> 7, rem = tid & 127;
    int b = rem >> 5, tp = ((rem >> 4) & 1) ? 17 : 0, c4 = (rem & 15) * 4;
    *(uint2*)&As[((nd * 4 + b) * 18 + tp) * XR + c4] = make_uint2(0, 0);
  }
  const uint4* ag4 = (const uint4*)agg;
  #pragma unroll
  for (int q = 0; q < 4; ++q) {
    int u = q * 256 + tid;
    int nd = u >> 9, rem = u & 511;
    int b = rem >> 7, r = rem & 127, tau = r >> 3, c0 = (r & 7) * 8;
    uint4 v = ag4[(size_t)(n0 + nd) * 512 + rem];
    *(uint4*)&As[((nd * 4 + b) * 18 + tau + 1) * XR + c0] = v;
  }
  __syncthreads();

  float bv = b2[w * 16 + m], bgate = b2[64 + w * 16 + m];
  float p1 = 0.f, p2 = 0.f;

  #pragma unroll
  for (int nd = 0; nd < MPB; ++nd) {
    int n = n0 + nd, nd4 = nd * 4;
    // residual loads issued at conv start: in flight under the conv (no barrier between)
    float xr[4][4];
    #pragma unroll
    for (int rt = 0; rt < 4; ++rt) {
      const float* xb = x + ((size_t)rt * NN + n) * 1024 + w * 16 + m;
      #pragma unroll
      for (int i = 0; i < 4; ++i)
        xr[rt][i] = xb[(4 * g4 + i) * 64];
    }
    f32x4 acc[4][2];
    #pragma unroll
    for (int rt = 0; rt < 4; ++rt) {
      acc[rt][0] = (f32x4){bv, bv, bv, bv};
      acc[rt][1] = (f32x4){bgate, bgate, bgate, bgate};
    }
    #pragma unroll
    for (int s = 0; s < 6; ++s) {
      const int kk = s >> 1, sp = s & 1;
      int col = 32 * sp + 4 * g4;
      #pragma unroll
      for (int rt = 0; rt < 4; ++rt) {
        int r0 = ((nd4 + rt) * 18 + m + kk) * XR + col;
        ABu a;
        a.u2[0] = *(const uint2*)&As[r0];
        a.u2[1] = *(const uint2*)&As[r0 + 16];
        acc[rt][0] = __builtin_amdgcn_mfma_f32_16x16x32_bf16(a.v, bc[s][0], acc[rt][0], 0, 0, 0);
        acc[rt][1] = __builtin_amdgcn_mfma_f32_16x16x32_bf16(a.v, bc[s][1], acc[rt][1], 0, 0, 0);
      }
    }
    // epilogue: GLU + residual + out + stats (registers only; col o = w*16+m)
    #pragma unroll
    for (int rt = 0; rt < 4; ++rt)
      #pragma unroll
      for (int i = 0; i < 4; ++i) {
        float v = acc[rt][0][i], gt = acc[rt][1][i];
        float h = v / (1.f + __expf(-gt));
        int t = 4 * g4 + i;
        float res = h + xr[rt][i];
        out[((rt * NN + n) * 16 + t) * 64 + w * 16 + m] = res;
        p1 += res;
        p2 += res * res;
      }
  }
  // stats: thread owns one column o = w*16+m; reduce over g4 groups via LDS
  red[(w * 16 + m) * 4 + g4] = p1;
  red[256 + (w * 16 + m) * 4 + g4] = p2;
  __syncthreads();
  if (tid < 64) {
    float s = red[tid * 4] + red[tid * 4 + 1] + red[tid * 4 + 2] + red[tid * 4 + 3];
    partials[tid * (NN / MPB) + blockIdx.x] = s;
  } else if (tid < 128) {
    int c = tid - 64;
    float s = red[256 + c * 4] + red[256 + c * 4 + 1] + red[256 + c * 4 + 2] + red[256 + c * 4 + 3];
    partials[(64 + c) * (NN / MPB) + blockIdx.x] = s;
  }
}

// ---------------- reduce partials -> chan[128] ----------------
__global__ __launch_bounds__(256) void k_reduce(const float* __restrict__ partials,
                                                float* __restrict__ chan) {
  __shared__ float sm[256];
  int r = blockIdx.x, tid = threadIdx.x;
  const float* p = partials + (size_t)r * (NN / MPB);
  float s = 0.f;
  for (int i = tid; i < NN / MPB; i += 256) s += p[i];
  sm[tid] = s;
  __syncthreads();
  for (int w = 128; w >= 1; w >>= 1) {
    if (tid < w) sm[tid] += sm[tid + w];
    __syncthreads();
  }
  if (tid == 0) chan[r] = sm[0];
}

// ---------------- layernorm (global per-channel stats) + relu, in place ----------------
__global__ __launch_bounds__(256) void k_norm(
    float* __restrict__ out, const float* __restrict__ chan,
    const float* __restrict__ gamma, const float* __restrict__ beta) {
  __shared__ float sc[64], sh[64];
  int tid = threadIdx.x;
  if (tid < 64) {
    const float inv = 1.f / (float)(NB * NN * NT);
    float mean = chan[tid] * inv;
    float var = chan[64 + tid] * inv - mean * mean;
    float s = rsqrtf(var + 1e-5f) * gamma[tid];
    sc[tid] = s;
    sh[tid] = beta[tid] - mean * s;
  }
  __syncthreads();
  float4* o4 = (float4*)out;
  const int total = NB * NN * NT * 16;
  for (int i = blockIdx.x * blockDim.x + threadIdx.x; i < total;
       i += gridDim.x * blockDim.x) {
    float4 v = o4[i];
    int c = (i * 4) & 63;
    v.x = fmaxf(v.x * sc[c + 0] + sh[c + 0], 0.f);
    v.y = fmaxf(v.y * sc[c + 1] + sh[c + 1], 0.f);
    v.z = fmaxf(v.z * sc[c + 2] + sh[c + 2], 0.f);
    v.w = fmaxf(v.w * sc[c + 3] + sh[c + 3], 0.f);
    o4[i] = v;
  }
}

// ---------------- launch ----------------

extern "C" void kernel_launch(void* const* d_in, const int* in_sizes, int n_in,
                              void* d_out, int out_size, void* d_ws, size_t ws_size,
                              hipStream_t stream) {
  const float* x    = (const float*)d_in[0];
  const int* esrc   = (const int*)d_in[1];
  const int* edst   = (const int*)d_in[2];
  const float* ew   = (const float*)d_in[3];
  const float* W1   = (const float*)d_in[4];
  const float* b1   = (const float*)d_in[5];
  const float* Wg   = (const float*)d_in[6];
  const float* bg   = (const float*)d_in[7];
  const float* W2   = (const float*)d_in[8];
  const float* b2   = (const float*)d_in[9];
  const float* gamma = (const float*)d_in[10];
  const float* beta  = (const float*)d_in[11];
  float* out = (float*)d_out;

  ushort* y_bf   = (ushort*)d_ws;          // 16777216 bf16 (node-major); dead after gather
  ushort* agg_bf = y_bf + 16777216;        // 16777216 bf16 (node-major)
  ushort* Bp1    = agg_bf + 16777216;      // 24576
  ushort* Bp2    = Bp1 + 24576;            // 24576
  ushort* Wgp    = Bp2 + 24576;            // 4096
  float* chan    = (float*)(Wgp + 4096);   // 128
  int* count   = (int*)(chan + 128);       // 4096
  int* offsets = count + 4096;             // 4097
  int* cursor  = offsets + 4097;           // 4096
  int* dsts    = cursor + 4096;            // 32768 (pre-sorted edge dst)
  float* wsrt  = (float*)(dsts + NE);      // 32768 (pre-sorted edge weight)
  float* partials = (float*)y_bf;          // 128*(NN/MPB) floats, aliases dead y

  hipLaunchKernelGGL(k_prep, dim3(128), dim3(256), 0, stream, W1, W2, Wg, Bp1, Bp2, Wgp, count);
  hipLaunchKernelGGL(k_count, dim3(128), dim3(256), 0, stream, esrc, count);
  hipLaunchKernelGGL(k_scan, dim3(1), dim3(256), 0, stream, count, offsets, cursor);
  hipLaunchKernelGGL(k_place, dim3(128), dim3(256), 0, stream, esrc, edst, ew, cursor, dsts, wsrt);
  hipLaunchKernelGGL(k_glu1lin, dim3(NN / MPB), dim3(256), 0, stream,
                     x, Bp1, b1, Wgp, bg, y_bf);
  hipLaunchKernelGGL(k_gather, dim3(NN * 2), dim3(256), 0, stream,
                     y_bf, offsets, dsts, wsrt, agg_bf);
  hipLaunchKernelGGL(k_glu2, dim3(NN / MPB), dim3(256), 0, stream,
                     agg_bf, x, Bp2, b2, out, partials);
  hipLaunchKernelGGL(k_reduce, dim3(128), dim3(256), 0, stream, partials, chan);
  hipLaunchKernelGGL(k_norm, dim3(2048), dim3(256), 0, stream,
                     out, chan, gamma, beta);
}